// Round 2
// baseline (39.016 us; speedup 1.0000x reference)
//
#include <hip/hip_runtime.h>

// Live computation of the reference (everything else is dead code):
//   inpt[384] = concat(x[64], prev_output[64], state[256])
//   h1[1024]  = relu(w1_0 @ inpt + b1_0)   w1_0: (1024,384) row-major
//   h2[1024]  = relu(w1_1 @ h1   + b1_1)   w1_1: (1024,1024)
//   out[64]   = relu(w1_2 @ h2   + b1_2)   w1_2: (64,1024)
//
// Single fused kernel, grid-wide epoch barrier in d_ws (reset each call by an
// async memset node). 256 blocks x 256 threads: capacity >= 8 blocks/CU on
// 256 CUs -> all blocks co-resident, spin barrier cannot deadlock.

#define GRID 256

__device__ __forceinline__ float wave_reduce_sum(float v) {
    v += __shfl_xor(v, 32, 64);
    v += __shfl_xor(v, 16, 64);
    v += __shfl_xor(v, 8, 64);
    v += __shfl_xor(v, 4, 64);
    v += __shfl_xor(v, 2, 64);
    v += __shfl_xor(v, 1, 64);
    return v;
}

// Epoch barrier: counter starts at 0 (memset each call). Each use adds GRID.
// old/GRID = epoch -> wait until (epoch+1)*GRID. Monotonic within a call.
__device__ __forceinline__ unsigned long long bar_arrive(unsigned long long* ctr) {
    __syncthreads();
    unsigned long long old = 0;
    if (threadIdx.x == 0) {
        __threadfence();  // release all prior writes (agent scope)
        old = __hip_atomic_fetch_add(ctr, 1ULL, __ATOMIC_ACQ_REL,
                                     __HIP_MEMORY_SCOPE_AGENT);
    }
    return old;  // valid on thread 0 only
}

__device__ __forceinline__ void bar_wait(unsigned long long* ctr,
                                         unsigned long long old) {
    if (threadIdx.x == 0) {
        unsigned long long target = (old / GRID + 1) * (unsigned long long)GRID;
        while (__hip_atomic_load(ctr, __ATOMIC_ACQUIRE,
                                 __HIP_MEMORY_SCOPE_AGENT) < target) {
            __builtin_amdgcn_s_sleep(1);
        }
        __threadfence();  // acquire: subsequent plain loads see released writes
    }
    __syncthreads();
}

__global__ void __launch_bounds__(256, 2) smrnn_fused(
        const float* __restrict__ x, const float* __restrict__ po,
        const float* __restrict__ st,
        const float* __restrict__ w0, const float* __restrict__ b0,
        const float* __restrict__ w1, const float* __restrict__ b1,
        const float* __restrict__ w2, const float* __restrict__ b2,
        float* __restrict__ h1, float* __restrict__ h2,
        float* __restrict__ out, unsigned long long* __restrict__ ctr) {
    __shared__ float s_in[1024];
    const int t = threadIdx.x;
    const int lane = t & 63;
    const int wave = t >> 6;
    const int blk = blockIdx.x;
    const int r = blk * 4 + wave;  // this wave's row for layers 1 & 2

    // ---- stage inpt[384] = concat(x, prev_output, state) ----
    for (int i = t; i < 384; i += 256) {
        float v;
        if (i < 64)       v = x[i];
        else if (i < 128) v = po[i - 64];
        else              v = st[i - 128];
        s_in[i] = v;
    }
    __syncthreads();

    // ---- layer 1: h1[r] = relu(w0[r,:] . inpt + b0[r]), K=384 ----
    {
        const float* wr = w0 + (size_t)r * 384;
        float acc = 0.f;
        {
            const int idx = lane * 4;  // first 256
            float4 wv = *reinterpret_cast<const float4*>(wr + idx);
            float4 iv = *reinterpret_cast<const float4*>(s_in + idx);
            acc += wv.x * iv.x + wv.y * iv.y + wv.z * iv.z + wv.w * iv.w;
        }
        {
            const int idx = 256 + lane * 2;  // last 128
            float2 wv = *reinterpret_cast<const float2*>(wr + idx);
            float2 iv = *reinterpret_cast<const float2*>(s_in + idx);
            acc += wv.x * iv.x + wv.y * iv.y;
        }
        acc = wave_reduce_sum(acc);
        if (lane == 0) h1[r] = fmaxf(acc + b0[r], 0.f);
    }

    // ---- barrier 1 (all blocks) ----
    bar_wait(ctr, bar_arrive(ctr));

    // ---- stage h1 into LDS ----
    for (int i = t; i < 1024; i += 256) s_in[i] = h1[i];
    __syncthreads();

    // ---- layer 2: h2[r] = relu(w1[r,:] . h1 + b1[r]), K=1024 ----
    {
        const float* wr = w1 + (size_t)r * 1024;
        float acc = 0.f;
#pragma unroll
        for (int it = 0; it < 4; ++it) {
            const int idx = it * 256 + lane * 4;
            float4 wv = *reinterpret_cast<const float4*>(wr + idx);
            float4 iv = *reinterpret_cast<const float4*>(s_in + idx);
            acc += wv.x * iv.x + wv.y * iv.y + wv.z * iv.z + wv.w * iv.w;
        }
        acc = wave_reduce_sum(acc);
        if (lane == 0) h2[r] = fmaxf(acc + b1[r], 0.f);
    }

    // ---- barrier 2: blocks >= 16 arrive and exit; blocks 0..15 wait ----
    unsigned long long old = bar_arrive(ctr);
    if (blk >= 16) return;
    bar_wait(ctr, old);

    // ---- stage h2 into LDS ----
    for (int i = t; i < 1024; i += 256) s_in[i] = h2[i];
    __syncthreads();

    // ---- layer 3: out[r3] = relu(w2[r3,:] . h2 + b2[r3]), 64 rows ----
    {
        const int r3 = blk * 4 + wave;  // [0,64)
        const float* wr = w2 + (size_t)r3 * 1024;
        float acc = 0.f;
#pragma unroll
        for (int it = 0; it < 4; ++it) {
            const int idx = it * 256 + lane * 4;
            float4 wv = *reinterpret_cast<const float4*>(wr + idx);
            float4 iv = *reinterpret_cast<const float4*>(s_in + idx);
            acc += wv.x * iv.x + wv.y * iv.y + wv.z * iv.z + wv.w * iv.w;
        }
        acc = wave_reduce_sum(acc);
        if (lane == 0) out[r3] = fmaxf(acc + b2[r3], 0.f);
    }
}

extern "C" void kernel_launch(void* const* d_in, const int* in_sizes, int n_in,
                              void* d_out, int out_size, void* d_ws, size_t ws_size,
                              hipStream_t stream) {
    // setup_inputs() dict order:
    // 0:x 1:w1_0 2:b1_0 3:w1_1 4:b1_1 5:w1_2 6:b1_2
    // 7..16: w2_*/b2_*  17..26: w3_*/b3_*
    // 27: prev_output 28: state 29: prev_weight_change 30: prev_bias_change
    const float* x    = (const float*)d_in[0];
    const float* w1_0 = (const float*)d_in[1];
    const float* b1_0 = (const float*)d_in[2];
    const float* w1_1 = (const float*)d_in[3];
    const float* b1_1 = (const float*)d_in[4];
    const float* w1_2 = (const float*)d_in[5];
    const float* b1_2 = (const float*)d_in[6];
    const float* po   = (const float*)d_in[27];
    const float* st   = (const float*)d_in[28];

    float* out = (float*)d_out;                      // 64 floats
    unsigned long long* ctr = (unsigned long long*)d_ws;
    float* h1 = (float*)d_ws + 64;                   // own cache line for ctr
    float* h2 = h1 + 1024;

    // Reset barrier counter every call (capture-legal, deterministic).
    hipMemsetAsync(d_ws, 0, 64, stream);
    smrnn_fused<<<GRID, 256, 0, stream>>>(x, po, st,
                                          w1_0, b1_0, w1_1, b1_1, w1_2, b1_2,
                                          h1, h2, out, ctr);
}

// Round 3
// 19.092 us; speedup vs baseline: 2.0436x; 2.0436x over previous
//
#include <hip/hip_runtime.h>

// Live computation of the reference (everything else is dead code):
//   inpt[384] = concat(x[64], prev_output[64], state[256])
//   h1[1024]  = relu(w1_0 @ inpt + b1_0)   w1_0: (1024,384) row-major
//   h2[1024]  = relu(w1_1 @ h1   + b1_1)   w1_1: (1024,1024)
//   out[64]   = relu(w1_2 @ h2   + b1_2)   w1_2: (64,1024)
//
// Two dispatches. K2 folds layer 3 in via K-decomposition: block b owns h2
// rows 4b..4b+3 (kept in LDS only), atomicAdds its partial contribution to
// the 64 pre-activations, and the LAST block to arrive (atomic counter, no
// spinning) applies bias+ReLU. Layer-2 pre-activation is linear in h2, so
// the K-split is exact up to fp32 atomic reassociation (~1e-5 << threshold).

#define GRID2 256

__device__ __forceinline__ float wave_reduce_sum(float v) {
    v += __shfl_xor(v, 32, 64);
    v += __shfl_xor(v, 16, 64);
    v += __shfl_xor(v, 8, 64);
    v += __shfl_xor(v, 4, 64);
    v += __shfl_xor(v, 2, 64);
    v += __shfl_xor(v, 1, 64);
    return v;
}

// K1: layer 1 (1024 rows, K=384), plus zero-init of out[64] and the arrival
// counter so no memset node is needed. 256 blocks x 256 threads.
__global__ void __launch_bounds__(256) k1_layer1(
        const float* __restrict__ x, const float* __restrict__ po,
        const float* __restrict__ st,
        const float* __restrict__ w0, const float* __restrict__ b0,
        float* __restrict__ h1, float* __restrict__ out,
        unsigned int* __restrict__ ctr) {
    __shared__ float s_in[384];
    const int t = threadIdx.x;

    if (blockIdx.x == 0) {
        if (t < 64) out[t] = 0.f;
        if (t == 0) *ctr = 0u;
    }

    for (int i = t; i < 384; i += 256) {
        float v;
        if (i < 64)       v = x[i];
        else if (i < 128) v = po[i - 64];
        else              v = st[i - 128];
        s_in[i] = v;
    }
    __syncthreads();

    const int lane = t & 63;
    const int wave = t >> 6;
    const int r = blockIdx.x * 4 + wave;  // [0,1024)

    const float* wr = w0 + (size_t)r * 384;
    float acc = 0.f;
    {
        const int idx = lane * 4;  // first 256 floats
        float4 wv = *reinterpret_cast<const float4*>(wr + idx);
        float4 iv = *reinterpret_cast<const float4*>(s_in + idx);
        acc += wv.x * iv.x + wv.y * iv.y + wv.z * iv.z + wv.w * iv.w;
    }
    {
        const int idx = 256 + lane * 2;  // last 128 floats
        float2 wv = *reinterpret_cast<const float2*>(wr + idx);
        float2 iv = *reinterpret_cast<const float2*>(s_in + idx);
        acc += wv.x * iv.x + wv.y * iv.y;
    }
    acc = wave_reduce_sum(acc);
    if (lane == 0) h1[r] = fmaxf(acc + b0[r], 0.f);
}

// K2: layer 2 rows in LDS + layer 3 partial via atomicAdd + last-block
// finalize (bias + ReLU). 256 blocks x 256 threads.
__global__ void __launch_bounds__(256) k2_layer23(
        const float* __restrict__ w1, const float* __restrict__ b1,
        const float* __restrict__ w2, const float* __restrict__ b2,
        const float* __restrict__ h1, float* __restrict__ out,
        unsigned int* __restrict__ ctr) {
    __shared__ float s_in[1024];
    __shared__ float s_h2[4];
    __shared__ unsigned int s_old;

    const int t = threadIdx.x;
    const int lane = t & 63;
    const int wave = t >> 6;
    const int blk = blockIdx.x;

    // stage h1 (float4-coalesced)
    {
        float4 v = *reinterpret_cast<const float4*>(h1 + t * 4);
        *reinterpret_cast<float4*>(s_in + t * 4) = v;
    }
    __syncthreads();

    // layer 2: row r = blk*4 + wave, K=1024
    {
        const int r = blk * 4 + wave;
        const float* wr = w1 + (size_t)r * 1024;
        float acc = 0.f;
#pragma unroll
        for (int it = 0; it < 4; ++it) {
            const int idx = it * 256 + lane * 4;
            float4 wv = *reinterpret_cast<const float4*>(wr + idx);
            float4 iv = *reinterpret_cast<const float4*>(s_in + idx);
            acc += wv.x * iv.x + wv.y * iv.y + wv.z * iv.z + wv.w * iv.w;
        }
        acc = wave_reduce_sum(acc);
        if (lane == 0) s_h2[wave] = fmaxf(acc + b1[r], 0.f);
    }
    __syncthreads();

    // layer 3 partial: lane j of wave 0 accumulates w2[j, 4b..4b+3] . s_h2
    if (wave == 0) {
        const float* w2r = w2 + (size_t)lane * 1024 + blk * 4;
        float4 wv = *reinterpret_cast<const float4*>(w2r);
        float p = wv.x * s_h2[0] + wv.y * s_h2[1] + wv.z * s_h2[2] + wv.w * s_h2[3];
        atomicAdd(out + lane, p);
    }
    // drain the atomics (compiler emits s_waitcnt vmcnt(0) before s_barrier)
    __syncthreads();

    if (t == 0) {
        s_old = __hip_atomic_fetch_add(ctr, 1u, __ATOMIC_ACQ_REL,
                                       __HIP_MEMORY_SCOPE_AGENT);
    }
    __syncthreads();

    // last block to arrive finalizes: all other blocks' adds have drained
    // (their vmcnt(0) preceded their counter increment)
    if (s_old == GRID2 - 1 && wave == 0) {
        float pre = __hip_atomic_load(out + lane, __ATOMIC_ACQUIRE,
                                      __HIP_MEMORY_SCOPE_AGENT);
        out[lane] = fmaxf(pre + b2[lane], 0.f);
    }
}

extern "C" void kernel_launch(void* const* d_in, const int* in_sizes, int n_in,
                              void* d_out, int out_size, void* d_ws, size_t ws_size,
                              hipStream_t stream) {
    // setup_inputs() dict order:
    // 0:x 1:w1_0 2:b1_0 3:w1_1 4:b1_1 5:w1_2 6:b1_2
    // 7..16: w2_*/b2_*  17..26: w3_*/b3_*
    // 27: prev_output 28: state 29: prev_weight_change 30: prev_bias_change
    const float* x    = (const float*)d_in[0];
    const float* w1_0 = (const float*)d_in[1];
    const float* b1_0 = (const float*)d_in[2];
    const float* w1_1 = (const float*)d_in[3];
    const float* b1_1 = (const float*)d_in[4];
    const float* w1_2 = (const float*)d_in[5];
    const float* b1_2 = (const float*)d_in[6];
    const float* po   = (const float*)d_in[27];
    const float* st   = (const float*)d_in[28];

    float* out = (float*)d_out;                       // 64 floats
    unsigned int* ctr = (unsigned int*)d_ws;          // own cache line
    float* h1 = (float*)d_ws + 64;                    // 1024 floats

    k1_layer1<<<256, 256, 0, stream>>>(x, po, st, w1_0, b1_0, h1, out, ctr);
    k2_layer23<<<GRID2, 256, 0, stream>>>(w1_1, b1_1, w1_2, b1_2, h1, out, ctr);
}